// Round 1
// baseline (870.033 us; speedup 1.0000x reference)
//
#include <hip/hip_runtime.h>
#include <math.h>
#include <stdint.h>

#define HW 512
#define NACT 30

struct Maps {
    int src_i[64];
    int src_j[64];
    int mask[64];
    int aidx[64];
    int act_k[NACT];
};

static Maps make_maps() {
    Maps m;
    for (int k = 0; k < 64; k++) { m.src_i[k]=0; m.src_j[k]=0; m.mask[k]=0; m.aidx[k]=-1; }
    for (int i = 1; i <= 8; i++)
        for (int j = 1; j <= 8; j++) {
            int k = i*j-1;
            m.src_i[k]=i-1; m.src_j[k]=j-1; m.mask[k]=1;
        }
    int cnt=0;
    for (int k=0;k<64;k++) if (m.mask[k]) { m.aidx[k]=cnt; if (cnt < NACT) m.act_k[cnt]=k; cnt++; }
    return m;
}

// ---------------- K0: zero fs2 accumulator ---------------------------------------
__global__ __launch_bounds__(256) void k_zero(float* __restrict__ p, int n) {
    int i = blockIdx.x*256 + threadIdx.x;
    if (i < n) p[i] = 0.f;
}

// ---------------- K1: per-patch means fg  (8,32,64 patches of 64x64) -------------
__global__ __launch_bounds__(256) void k_fg(const float* __restrict__ x, float* __restrict__ fgw) {
    int blk = blockIdx.x;            // ((b*32 + c)*64 + k)
    int k = blk & 63;
    int bc = blk >> 6;
    int c = bc & 31;
    int b = bc >> 5;
    int pi = k >> 3, pj = k & 7;
    const float* xp = x + (size_t)(b*32+c)*HW*HW;
    int t = threadIdx.x;
    float s = 0.f;
    #pragma unroll
    for (int ii = 0; ii < 4; ii++) {
        int idx4 = t + 256*ii;          // float4 index within patch, 0..1023
        int y = idx4 >> 4;
        int xx = (idx4 & 15) * 4;
        float4 v = *(const float4*)(xp + (size_t)(pi*64 + y)*HW + pj*64 + xx);
        s += v.x + v.y + v.z + v.w;
    }
    for (int off = 32; off > 0; off >>= 1) s += __shfl_down(s, off);
    __shared__ float p[4];
    if ((t & 63) == 0) p[t >> 6] = s;
    __syncthreads();
    if (t == 0) {
        float tot = p[0]+p[1]+p[2]+p[3];
        fgw[(b*64 + k)*32 + c] = tot * (1.0f/4096.0f);
    }
}

// ---------------- K2: tiny gating MLP -> g (8,64,32) ------------------------------
__global__ void k_g(const float* __restrict__ fgw,
                    const float* __restrict__ w12a, const float* __restrict__ b12a,
                    const float* __restrict__ w12b, const float* __restrict__ b12b,
                    const float* __restrict__ w12c, const float* __restrict__ b12c,
                    float* __restrict__ g) {
    int b = blockIdx.x;
    int c = threadIdx.x;
    if (c >= 32) return;
    float fg[64];
    #pragma unroll
    for (int k = 0; k < 64; k++) fg[k] = fgw[(b*64+k)*32 + c];
    float g1[8], g2[8];
    #pragma unroll
    for (int o = 0; o < 8; o++) {
        float v = b12a[o];
        #pragma unroll
        for (int k2 = 0; k2 < 64; k2++) v += w12a[o*64+k2]*fg[k2];
        g1[o] = fmaxf(v, 0.f);
    }
    #pragma unroll
    for (int o = 0; o < 8; o++) {
        float v = b12b[o];
        #pragma unroll
        for (int k2 = 0; k2 < 8; k2++) v += w12b[o*8+k2]*g1[k2];
        g2[o] = fmaxf(v, 0.f);
    }
    for (int o = 0; o < 64; o++) {
        float v = b12c[o];
        #pragma unroll
        for (int k2 = 0; k2 < 8; k2++) v += w12c[o*8+k2]*g2[k2];
        g[(b*64+o)*32 + c] = 1.f / (1.f + expf(-v));
    }
}

// ---------------- K3: per-patch 3x3 SAME conv + relu -> B, FUSED fs2 partial -----
// phase 1 (conv): col = t&63, tl = t>>6 owns output rows tl*4 .. tl*4+3 (of 16-row tile)
// phase 2 (fs2):  n = t>>5, c = t&31 computes fs2[n][c] partial over the 1024 tile px
__global__ __launch_bounds__(256) void k_conv(
        const float* __restrict__ x, const float* __restrict__ w30,
        const float* __restrict__ b30, float* __restrict__ B,
        float* __restrict__ fs2g, Maps m) {
    int blk = blockIdx.x;         // b*30 + a
    int rt = blockIdx.y;          // 0..3 row tile of 16
    int a = blk % NACT, b = blk / NACT;
    int k = m.act_k[a];
    int spi = m.src_i[k], spj = m.src_j[k];
    int r0 = rt*16;

    __shared__ float wl2[32*9*8];   // [c][dydx][n] -> 8 n contiguous
    __shared__ float xs[8*18*66];   // [cc][row(18)][col(66)]; reused as B tile in phase 2

    int t = threadIdx.x;
    for (int idx = t; idx < 2304; idx += 256) {
        int c = idx / 72;
        int rem = idx - c*72;
        int dydx = rem >> 3;
        int n = rem & 7;
        wl2[idx] = w30[(n*32 + c)*9 + dydx];
    }

    int col = t & 63, tl = t >> 6;
    float acc[4][8];
    #pragma unroll
    for (int rr=0; rr<4; rr++)
        #pragma unroll
        for (int n=0;n<8;n++) acc[rr][n]=0.f;

    const float* xb = x + (size_t)b*32*HW*HW;

    for (int c0 = 0; c0 < 32; c0 += 8) {
        __syncthreads();
        for (int idx = t; idx < 8*18*66; idx += 256) {
            int cc = idx / (18*66);
            int rem = idx - cc*(18*66);
            int r = rem / 66;
            int ccol = rem - r*66;
            int pr = r0 - 1 + r;
            int pc = ccol - 1;
            float v = 0.f;
            if (pr >= 0 && pr < 64 && pc >= 0 && pc < 64)
                v = xb[(size_t)(c0+cc)*HW*HW + (size_t)(spi*64+pr)*HW + spj*64 + pc];
            xs[idx] = v;
        }
        __syncthreads();
        for (int cc = 0; cc < 8; cc++) {
            // 18 distinct x values cover all (rr,dy,dx) for this thread
            const float* xrow = xs + cc*1188 + (tl*4)*66 + col;
            float xv[6][3];
            #pragma unroll
            for (int r6 = 0; r6 < 6; r6++)
                #pragma unroll
                for (int d = 0; d < 3; d++)
                    xv[r6][d] = xrow[r6*66 + d];
            const float* wb = wl2 + (c0+cc)*72;
            #pragma unroll
            for (int dy = 0; dy < 3; dy++) {
                #pragma unroll
                for (int dx = 0; dx < 3; dx++) {
                    float4 wa0 = *(const float4*)(wb + (dy*3+dx)*8);
                    float4 wa1 = *(const float4*)(wb + (dy*3+dx)*8 + 4);
                    #pragma unroll
                    for (int rr = 0; rr < 4; rr++) {
                        float xvv = xv[rr+dy][dx];
                        acc[rr][0] = fmaf(xvv, wa0.x, acc[rr][0]);
                        acc[rr][1] = fmaf(xvv, wa0.y, acc[rr][1]);
                        acc[rr][2] = fmaf(xvv, wa0.z, acc[rr][2]);
                        acc[rr][3] = fmaf(xvv, wa0.w, acc[rr][3]);
                        acc[rr][4] = fmaf(xvv, wa1.x, acc[rr][4]);
                        acc[rr][5] = fmaf(xvv, wa1.y, acc[rr][5]);
                        acc[rr][6] = fmaf(xvv, wa1.z, acc[rr][6]);
                        acc[rr][7] = fmaf(xvv, wa1.w, acc[rr][7]);
                    }
                }
            }
        }
    }

    // ---- write B (bias+relu) to global AND to LDS (reuse xs: 8192 floats) ----
    __syncthreads();                 // last conv chunk done reading xs
    float* ldsB = xs;                // [n][row(16)][col(64)]
    float* Bp = B + (size_t)(b*NACT+a)*8*4096;
    #pragma unroll
    for (int rr=0; rr<4; rr++) {
        int yl = tl*4 + rr;
        int y = r0 + yl;
        #pragma unroll
        for (int n=0;n<8;n++) {
            float v = fmaxf(acc[rr][n] + b30[n], 0.f);
            Bp[n*4096 + y*64 + col] = v;
            ldsB[n*1024 + yl*64 + col] = v;
        }
    }
    __syncthreads();

    // ---- phase 2: fs2[n][c] partial over this 16x64 tile ----
    {
        int n2 = t >> 5, c2 = t & 31;
        const float* xr = xb + (size_t)c2*HW*HW + (size_t)(spi*64 + r0)*HW + spj*64;
        const float4* Bl = (const float4*)(ldsB + n2*1024);
        float facc = 0.f;
        #pragma unroll 4
        for (int p4 = 0; p4 < 256; p4++) {
            int r = p4 >> 4, cq = p4 & 15;
            float4 bv = Bl[p4];
            float4 xv = *(const float4*)(xr + r*HW + cq*4);
            facc = fmaf(bv.x, xv.x, facc);
            facc = fmaf(bv.y, xv.y, facc);
            facc = fmaf(bv.z, xv.z, facc);
            facc = fmaf(bv.w, xv.w, facc);
        }
        atomicAdd(&fs2g[(size_t)(b*NACT+a)*256 + n2*32 + c2], facc);
    }
}

// ---------------- K4b: fs2 -> fs3 -> fs5 -----------------------------------------
__global__ __launch_bounds__(256) void k_fs3(
        const float* __restrict__ fs2g,
        const float* __restrict__ w11, const float* __restrict__ b11,
        const float* __restrict__ w10, const float* __restrict__ b10,
        float* __restrict__ fs5, Maps m) {
    int blk = blockIdx.x;   // b*30+a
    int a = blk % NACT, b = blk / NACT;
    int k = m.act_k[a];
    __shared__ float fs2s[8*33], fs3s[8*33];
    int t = threadIdx.x;
    {
        int n = t >> 5, c = t & 31;
        fs2s[n*33+c] = fs2g[(size_t)(b*NACT+a)*256 + n*32 + c];
    }
    __syncthreads();
    {
        int o = t >> 5, c = t & 31;
        float v = b11[o];
        #pragma unroll
        for (int n=0;n<8;n++) v += w11[o*8+n]*fs2s[n*33+c];
        fs3s[o*33+c] = fmaxf(v, 0.f);
    }
    __syncthreads();
    {
        int cp = t >> 3, n = t & 7;
        float v = b10[cp];
        #pragma unroll
        for (int c=0;c<32;c++) v += w10[cp*32+c]*fs3s[n*33+c];
        fs5[((size_t)(b*64+k)*32 + cp)*8 + n] = fmaxf(v, 0.f);
    }
}

// ---------------- K5: fused fs6*g -> w31 -> BN -> relu -> +x -> out ---------------
// thread: r = t>>4 (row within 16-row tile), q = t&15 (4-px group); 32 o per thread
__global__ __launch_bounds__(256) void k_out(
        const float* __restrict__ x, const float* __restrict__ B,
        const float* __restrict__ fs5, const float* __restrict__ g,
        const float* __restrict__ w31, const float* __restrict__ b31,
        const float* __restrict__ gamma, const float* __restrict__ beta,
        const float* __restrict__ mean, const float* __restrict__ var,
        float* __restrict__ out, Maps m) {
    int blk = blockIdx.x;   // b*64 + ij
    int rt = blockIdx.y;    // 0..3
    int ij = blk & 63, b = blk >> 6;
    int i = ij >> 3, j = ij & 7;
    int K = (i+1)*(j+1) - 1;
    int aK = m.aidx[K];
    __shared__ float Ms[256];        // [o][n]
    __shared__ float ss2[32], sh2[32];
    int t = threadIdx.x;
    {
        int o = t >> 3, n = t & 7;
        const float* f5 = fs5 + (size_t)(b*64+K)*32*8;
        const float* gg = g + (size_t)(b*64+K)*32;
        float v = 0.f;
        #pragma unroll
        for (int c=0;c<32;c++) v += w31[o*32+c]*gg[c]*f5[c*8+n];
        Ms[o*8+n] = v;
    }
    if (t < 32) {
        float sc = rsqrtf(var[t] + 1e-5f) * gamma[t];
        ss2[t] = sc;
        sh2[t] = (b31[t] - mean[t])*sc + beta[t];   // fold conv bias + BN shift
    }
    __syncthreads();

    int r = t >> 4, q = t & 15;
    int y = rt*16 + r;
    int Y = i*64 + y;
    int X = j*64 + q*4;
    const float* Bp = B + (size_t)(b*NACT+aK)*8*4096 + y*64 + q*4;
    const float* xb = x + (size_t)b*32*HW*HW + (size_t)Y*HW + X;
    float* ob = out + (size_t)b*32*HW*HW + (size_t)Y*HW + X;

    float4 Bv[8];
    #pragma unroll
    for (int n=0;n<8;n++) Bv[n] = *(const float4*)(Bp + n*4096);

    #pragma unroll 4
    for (int o = 0; o < 32; o++) {
        float4 Ma = *(const float4*)(Ms + o*8);
        float4 Mb = *(const float4*)(Ms + o*8 + 4);
        float so = ss2[o], ho = sh2[o];
        float4 xv = *(const float4*)(xb + (size_t)o*HW*HW);
        float4 yv;
        yv.x = Bv[0].x*Ma.x + Bv[1].x*Ma.y + Bv[2].x*Ma.z + Bv[3].x*Ma.w
             + Bv[4].x*Mb.x + Bv[5].x*Mb.y + Bv[6].x*Mb.z + Bv[7].x*Mb.w;
        yv.y = Bv[0].y*Ma.x + Bv[1].y*Ma.y + Bv[2].y*Ma.z + Bv[3].y*Ma.w
             + Bv[4].y*Mb.x + Bv[5].y*Mb.y + Bv[6].y*Mb.z + Bv[7].y*Mb.w;
        yv.z = Bv[0].z*Ma.x + Bv[1].z*Ma.y + Bv[2].z*Ma.z + Bv[3].z*Ma.w
             + Bv[4].z*Mb.x + Bv[5].z*Mb.y + Bv[6].z*Mb.z + Bv[7].z*Mb.w;
        yv.w = Bv[0].w*Ma.x + Bv[1].w*Ma.y + Bv[2].w*Ma.z + Bv[3].w*Ma.w
             + Bv[4].w*Mb.x + Bv[5].w*Mb.y + Bv[6].w*Mb.z + Bv[7].w*Mb.w;
        float4 res;
        res.x = fmaxf(yv.x*so + ho, 0.f) + xv.x;
        res.y = fmaxf(yv.y*so + ho, 0.f) + xv.y;
        res.z = fmaxf(yv.z*so + ho, 0.f) + xv.z;
        res.w = fmaxf(yv.w*so + ho, 0.f) + xv.w;
        *(float4*)(ob + (size_t)o*HW*HW) = res;
    }
}

extern "C" void kernel_launch(void* const* d_in, const int* in_sizes, int n_in,
                              void* d_out, int out_size, void* d_ws, size_t ws_size,
                              hipStream_t stream) {
    const float* x    = (const float*)d_in[0];
    const float* w30  = (const float*)d_in[1];
    const float* b30  = (const float*)d_in[2];
    const float* w10  = (const float*)d_in[3];
    const float* b10  = (const float*)d_in[4];
    const float* w11  = (const float*)d_in[5];
    const float* b11  = (const float*)d_in[6];
    const float* w12a = (const float*)d_in[7];
    const float* b12a = (const float*)d_in[8];
    const float* w12b = (const float*)d_in[9];
    const float* b12b = (const float*)d_in[10];
    const float* w12c = (const float*)d_in[11];
    const float* b12c = (const float*)d_in[12];
    const float* w31  = (const float*)d_in[13];
    const float* b31  = (const float*)d_in[14];
    const float* gam  = (const float*)d_in[15];
    const float* bet  = (const float*)d_in[16];
    const float* mea  = (const float*)d_in[17];
    const float* var  = (const float*)d_in[18];
    float* out = (float*)d_out;

    float* ws   = (float*)d_ws;
    float* B    = ws;                       // 8*30*8*4096 = 7,864,320 floats
    float* fs5  = B + 7864320;              // 8*64*32*8   =   131,072
    float* fgw  = fs5 + 131072;             // 8*64*32     =    16,384
    float* g    = fgw + 16384;              // 8*64*32     =    16,384
    float* fs2g = g + 16384;                // 8*30*256    =    61,440

    static Maps m = make_maps();

    k_zero<<<dim3(240),    256, 0, stream>>>(fs2g, 61440);
    k_fg  <<<dim3(16384),  256, 0, stream>>>(x, fgw);
    k_g   <<<dim3(8),       64, 0, stream>>>(fgw, w12a, b12a, w12b, b12b, w12c, b12c, g);
    k_conv<<<dim3(240, 4), 256, 0, stream>>>(x, w30, b30, B, fs2g, m);
    k_fs3 <<<dim3(240),    256, 0, stream>>>(fs2g, w11, b11, w10, b10, fs5, m);
    k_out <<<dim3(512, 4), 256, 0, stream>>>(x, B, fs5, g, w31, b31, gam, bet, mea, var, out, m);
}

// Round 2
// 762.067 us; speedup vs baseline: 1.1417x; 1.1417x over previous
//
#include <hip/hip_runtime.h>
#include <math.h>
#include <stdint.h>

#define HW 512
#define NACT 30

struct Maps {
    int src_i[64];
    int src_j[64];
    int mask[64];
    int aidx[64];
    int act_k[NACT];
};

static Maps make_maps() {
    Maps m;
    for (int k = 0; k < 64; k++) { m.src_i[k]=0; m.src_j[k]=0; m.mask[k]=0; m.aidx[k]=-1; }
    for (int i = 1; i <= 8; i++)
        for (int j = 1; j <= 8; j++) {
            int k = i*j-1;
            m.src_i[k]=i-1; m.src_j[k]=j-1; m.mask[k]=1;
        }
    int cnt=0;
    for (int k=0;k<64;k++) if (m.mask[k]) { m.aidx[k]=cnt; if (cnt < NACT) m.act_k[cnt]=k; cnt++; }
    return m;
}

// ---------------- K0: zero fs2 accumulator ---------------------------------------
__global__ __launch_bounds__(256) void k_zero(float* __restrict__ p, int n) {
    int i = blockIdx.x*256 + threadIdx.x;
    if (i < n) p[i] = 0.f;
}

// ---------------- K1: per-patch means fg  (8,32,64 patches of 64x64) -------------
__global__ __launch_bounds__(256) void k_fg(const float* __restrict__ x, float* __restrict__ fgw) {
    int blk = blockIdx.x;            // ((b*32 + c)*64 + k)
    int k = blk & 63;
    int bc = blk >> 6;
    int c = bc & 31;
    int b = bc >> 5;
    int pi = k >> 3, pj = k & 7;
    const float* xp = x + (size_t)(b*32+c)*HW*HW;
    int t = threadIdx.x;
    float s = 0.f;
    #pragma unroll
    for (int ii = 0; ii < 4; ii++) {
        int idx4 = t + 256*ii;          // float4 index within patch, 0..1023
        int y = idx4 >> 4;
        int xx = (idx4 & 15) * 4;
        float4 v = *(const float4*)(xp + (size_t)(pi*64 + y)*HW + pj*64 + xx);
        s += v.x + v.y + v.z + v.w;
    }
    for (int off = 32; off > 0; off >>= 1) s += __shfl_down(s, off);
    __shared__ float p[4];
    if ((t & 63) == 0) p[t >> 6] = s;
    __syncthreads();
    if (t == 0) {
        float tot = p[0]+p[1]+p[2]+p[3];
        fgw[(b*64 + k)*32 + c] = tot * (1.0f/4096.0f);
    }
}

// ---------------- K2: tiny gating MLP -> g (8,64,32) ------------------------------
__global__ void k_g(const float* __restrict__ fgw,
                    const float* __restrict__ w12a, const float* __restrict__ b12a,
                    const float* __restrict__ w12b, const float* __restrict__ b12b,
                    const float* __restrict__ w12c, const float* __restrict__ b12c,
                    float* __restrict__ g) {
    int b = blockIdx.x;
    int c = threadIdx.x;
    if (c >= 32) return;
    float fg[64];
    #pragma unroll
    for (int k = 0; k < 64; k++) fg[k] = fgw[(b*64+k)*32 + c];
    float g1[8], g2[8];
    #pragma unroll
    for (int o = 0; o < 8; o++) {
        float v = b12a[o];
        #pragma unroll
        for (int k2 = 0; k2 < 64; k2++) v += w12a[o*64+k2]*fg[k2];
        g1[o] = fmaxf(v, 0.f);
    }
    #pragma unroll
    for (int o = 0; o < 8; o++) {
        float v = b12b[o];
        #pragma unroll
        for (int k2 = 0; k2 < 8; k2++) v += w12b[o*8+k2]*g1[k2];
        g2[o] = fmaxf(v, 0.f);
    }
    for (int o = 0; o < 64; o++) {
        float v = b12c[o];
        #pragma unroll
        for (int k2 = 0; k2 < 8; k2++) v += w12c[o*8+k2]*g2[k2];
        g[(b*64+o)*32 + c] = 1.f / (1.f + expf(-v));
    }
}

// ---------------- K3: per-patch 3x3 SAME conv + relu -> B (8-row tiles) ----------
// thread: col = t&63, tl = t>>6 owns output rows tl*2, tl*2+1 (within 8-row tile)
__global__ __launch_bounds__(256) void k_conv(
        const float* __restrict__ x, const float* __restrict__ w30,
        const float* __restrict__ b30, float* __restrict__ B, Maps m) {
    int blk = blockIdx.x;         // b*30 + a
    int rt = blockIdx.y;          // 0..7 row tile of 8
    int a = blk % NACT, b = blk / NACT;
    int k = m.act_k[a];
    int spi = m.src_i[k], spj = m.src_j[k];
    int r0 = rt*8;

    __shared__ float wl2[32*9*8];   // [c][dydx][n] -> 8 n contiguous  (2304 floats)
    __shared__ float xs[8*10*66];   // [cc][row(10)][col(66)]          (5280 floats)

    int t = threadIdx.x;
    for (int idx = t; idx < 2304; idx += 256) {
        int c = idx / 72;
        int rem = idx - c*72;
        int dydx = rem >> 3;
        int n = rem & 7;
        wl2[idx] = w30[(n*32 + c)*9 + dydx];
    }

    int col = t & 63, tl = t >> 6;
    float acc[2][8];
    #pragma unroll
    for (int rr=0; rr<2; rr++)
        #pragma unroll
        for (int n=0;n<8;n++) acc[rr][n]=0.f;

    const float* xb = x + (size_t)b*32*HW*HW;

    for (int c0 = 0; c0 < 32; c0 += 8) {
        __syncthreads();
        for (int idx = t; idx < 8*10*66; idx += 256) {
            int cc = idx / 660;
            int rem = idx - cc*660;
            int r = rem / 66;
            int ccol = rem - r*66;
            int pr = r0 - 1 + r;
            int pc = ccol - 1;
            float v = 0.f;
            if (pr >= 0 && pr < 64 && pc >= 0 && pc < 64)
                v = xb[(size_t)(c0+cc)*HW*HW + (size_t)(spi*64+pr)*HW + spj*64 + pc];
            xs[idx] = v;
        }
        __syncthreads();
        for (int cc = 0; cc < 8; cc++) {
            // 12 distinct x values cover all (rr,dy,dx) for this thread
            const float* xrow = xs + cc*660 + (tl*2)*66 + col;
            float xv[4][3];
            #pragma unroll
            for (int r4 = 0; r4 < 4; r4++)
                #pragma unroll
                for (int d = 0; d < 3; d++)
                    xv[r4][d] = xrow[r4*66 + d];
            const float* wb = wl2 + (c0+cc)*72;
            #pragma unroll
            for (int dy = 0; dy < 3; dy++) {
                #pragma unroll
                for (int dx = 0; dx < 3; dx++) {
                    float4 wa0 = *(const float4*)(wb + (dy*3+dx)*8);
                    float4 wa1 = *(const float4*)(wb + (dy*3+dx)*8 + 4);
                    #pragma unroll
                    for (int rr = 0; rr < 2; rr++) {
                        float xvv = xv[rr+dy][dx];
                        acc[rr][0] = fmaf(xvv, wa0.x, acc[rr][0]);
                        acc[rr][1] = fmaf(xvv, wa0.y, acc[rr][1]);
                        acc[rr][2] = fmaf(xvv, wa0.z, acc[rr][2]);
                        acc[rr][3] = fmaf(xvv, wa0.w, acc[rr][3]);
                        acc[rr][4] = fmaf(xvv, wa1.x, acc[rr][4]);
                        acc[rr][5] = fmaf(xvv, wa1.y, acc[rr][5]);
                        acc[rr][6] = fmaf(xvv, wa1.z, acc[rr][6]);
                        acc[rr][7] = fmaf(xvv, wa1.w, acc[rr][7]);
                    }
                }
            }
        }
    }
    float* Bp = B + (size_t)(b*NACT+a)*8*4096;
    #pragma unroll
    for (int rr=0; rr<2; rr++) {
        int y = r0 + tl*2 + rr;
        #pragma unroll
        for (int n=0;n<8;n++)
            Bp[n*4096 + y*64 + col] = fmaxf(acc[rr][n] + b30[n], 0.f);
    }
}

// ---------------- K4a: partial fs2 = B @ fs^T over L-chunk, atomic accumulate ----
__global__ __launch_bounds__(256) void k_fs2a(
        const float* __restrict__ x, const float* __restrict__ B,
        float* __restrict__ fs2g, Maps m) {
    int blk = blockIdx.x;   // b*30+a
    int rt = blockIdx.y;    // 0..7 -> chunks [rt*2, rt*2+2)
    int a = blk % NACT, b = blk / NACT;
    int k = m.act_k[a];
    int spi = m.src_i[k], spj = m.src_j[k];

    __shared__ float buf[10400];            // Bs(8*260) | xs(32*260), reused as partials
    float* Bs = buf;
    float* xs = buf + 8*260;

    int t = threadIdx.x;
    int cg = t >> 5, s = t & 31;
    float acc[8][4];
    #pragma unroll
    for (int n=0;n<8;n++)
        #pragma unroll
        for (int i=0;i<4;i++) acc[n][i]=0.f;

    const float4* Bg4 = (const float4*)(B + (size_t)(b*NACT+a)*8*4096);
    const float* xb = x + (size_t)b*32*HW*HW;

    for (int ch = rt*2; ch < rt*2+2; ch++) {
        int l0 = ch*256;
        __syncthreads();
        #pragma unroll
        for (int q = 0; q < 2; q++) {
            int i4 = t + 256*q;
            int n = i4 >> 6, lq = i4 & 63;
            ((float4*)(Bs + n*260))[lq] = Bg4[n*1024 + (l0>>2) + lq];
        }
        #pragma unroll
        for (int q = 0; q < 8; q++) {
            int i4 = t + 256*q;
            int c = i4 >> 6, lq = i4 & 63;
            int l = l0 + lq*4;
            int y = l >> 6, xx = l & 63;
            float4 v = *(const float4*)(xb + (size_t)c*HW*HW + (size_t)(spi*64+y)*HW + spj*64 + xx);
            ((float4*)(xs + c*260))[lq] = v;
        }
        __syncthreads();
        #pragma unroll
        for (int st = 0; st < 2; st++) {
            int q = s + 32*st;
            float4 bv[8];
            #pragma unroll
            for (int n=0;n<8;n++) bv[n] = ((const float4*)(Bs + n*260))[q];
            #pragma unroll
            for (int i=0;i<4;i++) {
                float4 xv = ((const float4*)(xs + (cg*4+i)*260))[q];
                #pragma unroll
                for (int n=0;n<8;n++) {
                    acc[n][i] = fmaf(bv[n].x, xv.x, acc[n][i]);
                    acc[n][i] = fmaf(bv[n].y, xv.y, acc[n][i]);
                    acc[n][i] = fmaf(bv[n].z, xv.z, acc[n][i]);
                    acc[n][i] = fmaf(bv[n].w, xv.w, acc[n][i]);
                }
            }
        }
    }
    __syncthreads();
    #pragma unroll
    for (int n=0;n<8;n++)
        #pragma unroll
        for (int i=0;i<4;i++)
            buf[(n*32 + cg*4+i)*32 + s] = acc[n][i];
    __syncthreads();
    {
        int n = t >> 5, c = t & 31;
        float v = 0.f;
        #pragma unroll
        for (int ss=0; ss<32; ss++) v += buf[(n*32+c)*32 + ss];
        atomicAdd(&fs2g[(size_t)(b*NACT+a)*256 + n*32 + c], v);
    }
}

// ---------------- K4b: fs2 -> fs3 -> fs5 -----------------------------------------
__global__ __launch_bounds__(256) void k_fs3(
        const float* __restrict__ fs2g,
        const float* __restrict__ w11, const float* __restrict__ b11,
        const float* __restrict__ w10, const float* __restrict__ b10,
        float* __restrict__ fs5, Maps m) {
    int blk = blockIdx.x;   // b*30+a
    int a = blk % NACT, b = blk / NACT;
    int k = m.act_k[a];
    __shared__ float fs2s[8*33], fs3s[8*33];
    int t = threadIdx.x;
    {
        int n = t >> 5, c = t & 31;
        fs2s[n*33+c] = fs2g[(size_t)(b*NACT+a)*256 + n*32 + c];
    }
    __syncthreads();
    {
        int o = t >> 5, c = t & 31;
        float v = b11[o];
        #pragma unroll
        for (int n=0;n<8;n++) v += w11[o*8+n]*fs2s[n*33+c];
        fs3s[o*33+c] = fmaxf(v, 0.f);
    }
    __syncthreads();
    {
        int cp = t >> 3, n = t & 7;
        float v = b10[cp];
        #pragma unroll
        for (int c=0;c<32;c++) v += w10[cp*32+c]*fs3s[n*33+c];
        fs5[((size_t)(b*64+k)*32 + cp)*8 + n] = fmaxf(v, 0.f);
    }
}

// ---------------- K5: fused fs6*g -> w31 -> BN -> relu -> +x -> out ---------------
// thread: r = t>>4 (row within 16-row tile), q = t&15 (4-px group); 32 o per thread
__global__ __launch_bounds__(256) void k_out(
        const float* __restrict__ x, const float* __restrict__ B,
        const float* __restrict__ fs5, const float* __restrict__ g,
        const float* __restrict__ w31, const float* __restrict__ b31,
        const float* __restrict__ gamma, const float* __restrict__ beta,
        const float* __restrict__ mean, const float* __restrict__ var,
        float* __restrict__ out, Maps m) {
    int blk = blockIdx.x;   // b*64 + ij
    int rt = blockIdx.y;    // 0..3
    int ij = blk & 63, b = blk >> 6;
    int i = ij >> 3, j = ij & 7;
    int K = (i+1)*(j+1) - 1;
    int aK = m.aidx[K];
    __shared__ float Ms[256];        // [o][n]
    __shared__ float ss2[32], sh2[32];
    int t = threadIdx.x;
    {
        int o = t >> 3, n = t & 7;
        const float* f5 = fs5 + (size_t)(b*64+K)*32*8;
        const float* gg = g + (size_t)(b*64+K)*32;
        float v = 0.f;
        #pragma unroll
        for (int c=0;c<32;c++) v += w31[o*32+c]*gg[c]*f5[c*8+n];
        Ms[o*8+n] = v;
    }
    if (t < 32) {
        float sc = rsqrtf(var[t] + 1e-5f) * gamma[t];
        ss2[t] = sc;
        sh2[t] = (b31[t] - mean[t])*sc + beta[t];   // fold conv bias + BN shift
    }
    __syncthreads();

    int r = t >> 4, q = t & 15;
    int y = rt*16 + r;
    int Y = i*64 + y;
    int X = j*64 + q*4;
    const float* Bp = B + (size_t)(b*NACT+aK)*8*4096 + y*64 + q*4;
    const float* xb = x + (size_t)b*32*HW*HW + (size_t)Y*HW + X;
    float* ob = out + (size_t)b*32*HW*HW + (size_t)Y*HW + X;

    float4 Bv[8];
    #pragma unroll
    for (int n=0;n<8;n++) Bv[n] = *(const float4*)(Bp + n*4096);

    #pragma unroll 4
    for (int o = 0; o < 32; o++) {
        float4 Ma = *(const float4*)(Ms + o*8);
        float4 Mb = *(const float4*)(Ms + o*8 + 4);
        float so = ss2[o], ho = sh2[o];
        float4 xv = *(const float4*)(xb + (size_t)o*HW*HW);
        float4 yv;
        yv.x = Bv[0].x*Ma.x + Bv[1].x*Ma.y + Bv[2].x*Ma.z + Bv[3].x*Ma.w
             + Bv[4].x*Mb.x + Bv[5].x*Mb.y + Bv[6].x*Mb.z + Bv[7].x*Mb.w;
        yv.y = Bv[0].y*Ma.x + Bv[1].y*Ma.y + Bv[2].y*Ma.z + Bv[3].y*Ma.w
             + Bv[4].y*Mb.x + Bv[5].y*Mb.y + Bv[6].y*Mb.z + Bv[7].y*Mb.w;
        yv.z = Bv[0].z*Ma.x + Bv[1].z*Ma.y + Bv[2].z*Ma.z + Bv[3].z*Ma.w
             + Bv[4].z*Mb.x + Bv[5].z*Mb.y + Bv[6].z*Mb.z + Bv[7].z*Mb.w;
        yv.w = Bv[0].w*Ma.x + Bv[1].w*Ma.y + Bv[2].w*Ma.z + Bv[3].w*Ma.w
             + Bv[4].w*Mb.x + Bv[5].w*Mb.y + Bv[6].w*Mb.z + Bv[7].w*Mb.w;
        float4 res;
        res.x = fmaxf(yv.x*so + ho, 0.f) + xv.x;
        res.y = fmaxf(yv.y*so + ho, 0.f) + xv.y;
        res.z = fmaxf(yv.z*so + ho, 0.f) + xv.z;
        res.w = fmaxf(yv.w*so + ho, 0.f) + xv.w;
        *(float4*)(ob + (size_t)o*HW*HW) = res;
    }
}

extern "C" void kernel_launch(void* const* d_in, const int* in_sizes, int n_in,
                              void* d_out, int out_size, void* d_ws, size_t ws_size,
                              hipStream_t stream) {
    const float* x    = (const float*)d_in[0];
    const float* w30  = (const float*)d_in[1];
    const float* b30  = (const float*)d_in[2];
    const float* w10  = (const float*)d_in[3];
    const float* b10  = (const float*)d_in[4];
    const float* w11  = (const float*)d_in[5];
    const float* b11  = (const float*)d_in[6];
    const float* w12a = (const float*)d_in[7];
    const float* b12a = (const float*)d_in[8];
    const float* w12b = (const float*)d_in[9];
    const float* b12b = (const float*)d_in[10];
    const float* w12c = (const float*)d_in[11];
    const float* b12c = (const float*)d_in[12];
    const float* w31  = (const float*)d_in[13];
    const float* b31  = (const float*)d_in[14];
    const float* gam  = (const float*)d_in[15];
    const float* bet  = (const float*)d_in[16];
    const float* mea  = (const float*)d_in[17];
    const float* var  = (const float*)d_in[18];
    float* out = (float*)d_out;

    float* ws   = (float*)d_ws;
    float* B    = ws;                       // 8*30*8*4096 = 7,864,320 floats
    float* fs5  = B + 7864320;              // 8*64*32*8   =   131,072
    float* fgw  = fs5 + 131072;             // 8*64*32     =    16,384
    float* g    = fgw + 16384;              // 8*64*32     =    16,384
    float* fs2g = g + 16384;                // 8*30*256    =    61,440

    static Maps m = make_maps();

    k_zero<<<dim3(240),    256, 0, stream>>>(fs2g, 61440);
    k_fg  <<<dim3(16384),  256, 0, stream>>>(x, fgw);
    k_g   <<<dim3(8),       64, 0, stream>>>(fgw, w12a, b12a, w12b, b12b, w12c, b12c, g);
    k_conv<<<dim3(240, 8), 256, 0, stream>>>(x, w30, b30, B, m);
    k_fs2a<<<dim3(240, 8), 256, 0, stream>>>(x, B, fs2g, m);
    k_fs3 <<<dim3(240),    256, 0, stream>>>(fs2g, w11, b11, w10, b10, fs5, m);
    k_out <<<dim3(512, 4), 256, 0, stream>>>(x, B, fs5, g, w31, b31, gam, bet, mea, var, out, m);
}

// Round 3
// 730.887 us; speedup vs baseline: 1.1904x; 1.0427x over previous
//
#include <hip/hip_runtime.h>
#include <math.h>
#include <stdint.h>

#define HW 512
#define NACT 30

struct Maps {
    int src_i[64];
    int src_j[64];
    int mask[64];
    int aidx[64];
    int act_k[NACT];
};

static Maps make_maps() {
    Maps m;
    for (int k = 0; k < 64; k++) { m.src_i[k]=0; m.src_j[k]=0; m.mask[k]=0; m.aidx[k]=-1; }
    for (int i = 1; i <= 8; i++)
        for (int j = 1; j <= 8; j++) {
            int k = i*j-1;
            m.src_i[k]=i-1; m.src_j[k]=j-1; m.mask[k]=1;
        }
    int cnt=0;
    for (int k=0;k<64;k++) if (m.mask[k]) { m.aidx[k]=cnt; if (cnt < NACT) m.act_k[cnt]=k; cnt++; }
    return m;
}

// ---------------- K0: zero fs2 accumulator ---------------------------------------
__global__ __launch_bounds__(256) void k_zero(float* __restrict__ p, int n) {
    int i = blockIdx.x*256 + threadIdx.x;
    if (i < n) p[i] = 0.f;
}

// ---------------- K1: per-patch means fg  (8,32,64 patches of 64x64) -------------
__global__ __launch_bounds__(256) void k_fg(const float* __restrict__ x, float* __restrict__ fgw) {
    int blk = blockIdx.x;            // ((b*32 + c)*64 + k)
    int k = blk & 63;
    int bc = blk >> 6;
    int c = bc & 31;
    int b = bc >> 5;
    int pi = k >> 3, pj = k & 7;
    const float* xp = x + (size_t)(b*32+c)*HW*HW;
    int t = threadIdx.x;
    float s = 0.f;
    #pragma unroll
    for (int ii = 0; ii < 4; ii++) {
        int idx4 = t + 256*ii;          // float4 index within patch, 0..1023
        int y = idx4 >> 4;
        int xx = (idx4 & 15) * 4;
        float4 v = *(const float4*)(xp + (size_t)(pi*64 + y)*HW + pj*64 + xx);
        s += v.x + v.y + v.z + v.w;
    }
    for (int off = 32; off > 0; off >>= 1) s += __shfl_down(s, off);
    __shared__ float p[4];
    if ((t & 63) == 0) p[t >> 6] = s;
    __syncthreads();
    if (t == 0) {
        float tot = p[0]+p[1]+p[2]+p[3];
        fgw[(b*64 + k)*32 + c] = tot * (1.0f/4096.0f);
    }
}

// ---------------- K2: tiny gating MLP -> g (8,64,32) ------------------------------
__global__ void k_g(const float* __restrict__ fgw,
                    const float* __restrict__ w12a, const float* __restrict__ b12a,
                    const float* __restrict__ w12b, const float* __restrict__ b12b,
                    const float* __restrict__ w12c, const float* __restrict__ b12c,
                    float* __restrict__ g) {
    int b = blockIdx.x;
    int c = threadIdx.x;
    if (c >= 32) return;
    float fg[64];
    #pragma unroll
    for (int k = 0; k < 64; k++) fg[k] = fgw[(b*64+k)*32 + c];
    float g1[8], g2[8];
    #pragma unroll
    for (int o = 0; o < 8; o++) {
        float v = b12a[o];
        #pragma unroll
        for (int k2 = 0; k2 < 64; k2++) v += w12a[o*64+k2]*fg[k2];
        g1[o] = fmaxf(v, 0.f);
    }
    #pragma unroll
    for (int o = 0; o < 8; o++) {
        float v = b12b[o];
        #pragma unroll
        for (int k2 = 0; k2 < 8; k2++) v += w12b[o*8+k2]*g1[k2];
        g2[o] = fmaxf(v, 0.f);
    }
    for (int o = 0; o < 64; o++) {
        float v = b12c[o];
        #pragma unroll
        for (int k2 = 0; k2 < 8; k2++) v += w12c[o*8+k2]*g2[k2];
        g[(b*64+o)*32 + c] = 1.f / (1.f + expf(-v));
    }
}

// ---------------- K3: per-patch 3x3 SAME conv + relu -> B (8-row tiles) ----------
// Patch-SAME padding => halo rows/cols are constant ZERO: zero LDS once, stage only
// the interior as float4 (1280 f4/block = 5/thread). Per-chunk weights in LDS.
// thread: col = t&63, tl = t>>6 owns output rows tl*2, tl*2+1 (within 8-row tile)
__global__ __launch_bounds__(256) void k_conv(
        const float* __restrict__ x, const float* __restrict__ w30,
        const float* __restrict__ b30, float* __restrict__ B, Maps m) {
    int blk = blockIdx.x;         // b*30 + a
    int rt = blockIdx.y;          // 0..7 row tile of 8
    int a = blk % NACT, b = blk / NACT;
    int k = m.act_k[a];
    int spi = m.src_i[k], spj = m.src_j[k];
    int r0 = rt*8;

    __shared__ float wlc[576];                    // [cc][dydx][n] for current 8-ch chunk
    __shared__ __align__(16) float xs[8*10*72];   // [cc][row(10)][72]; interior at col' 4..67

    int t = threadIdx.x;
    // one-time zero: halo cols (3,68) and pad stay 0 forever; interior re-staged per chunk
    for (int idx = t; idx < 8*10*72; idx += 256) xs[idx] = 0.f;

    int col = t & 63, tl = t >> 6;
    float acc[2][8];
    #pragma unroll
    for (int rr=0; rr<2; rr++)
        #pragma unroll
        for (int n=0;n<8;n++) acc[rr][n]=0.f;

    const float* xb = x + (size_t)b*32*HW*HW;

    for (int c0 = 0; c0 < 32; c0 += 8) {
        __syncthreads();          // prev compute done (and initial zero done)
        // stage weights for this channel chunk
        for (int idx = t; idx < 576; idx += 256) {
            int cc = idx / 72;
            int rem = idx - cc*72;
            int dydx = rem >> 3;
            int n = rem & 7;
            wlc[idx] = w30[(n*32 + c0 + cc)*9 + dydx];
        }
        // stage x interior: 8 ch x 10 rows x 16 float4
        #pragma unroll
        for (int it = 0; it < 5; it++) {
            int idx = t + 256*it;            // 0..1279
            int cc = idx / 160;
            int rem = idx - cc*160;
            int r = rem >> 4;
            int q = rem & 15;
            int pr = r0 - 1 + r;
            float4 v = make_float4(0.f,0.f,0.f,0.f);
            if (pr >= 0 && pr < 64)
                v = *(const float4*)(xb + (size_t)(c0+cc)*HW*HW + (size_t)(spi*64+pr)*HW + spj*64 + q*4);
            *(float4*)(xs + cc*720 + r*72 + 4 + q*4) = v;
        }
        __syncthreads();
        for (int cc = 0; cc < 8; cc++) {
            const float* xrow = xs + cc*720 + (tl*2)*72 + 3 + col;
            float xv[4][3];
            #pragma unroll
            for (int r4 = 0; r4 < 4; r4++)
                #pragma unroll
                for (int d = 0; d < 3; d++)
                    xv[r4][d] = xrow[r4*72 + d];
            const float* wb = wlc + cc*72;
            #pragma unroll
            for (int dy = 0; dy < 3; dy++) {
                #pragma unroll
                for (int dx = 0; dx < 3; dx++) {
                    float4 wa0 = *(const float4*)(wb + (dy*3+dx)*8);
                    float4 wa1 = *(const float4*)(wb + (dy*3+dx)*8 + 4);
                    #pragma unroll
                    for (int rr = 0; rr < 2; rr++) {
                        float xvv = xv[rr+dy][dx];
                        acc[rr][0] = fmaf(xvv, wa0.x, acc[rr][0]);
                        acc[rr][1] = fmaf(xvv, wa0.y, acc[rr][1]);
                        acc[rr][2] = fmaf(xvv, wa0.z, acc[rr][2]);
                        acc[rr][3] = fmaf(xvv, wa0.w, acc[rr][3]);
                        acc[rr][4] = fmaf(xvv, wa1.x, acc[rr][4]);
                        acc[rr][5] = fmaf(xvv, wa1.y, acc[rr][5]);
                        acc[rr][6] = fmaf(xvv, wa1.z, acc[rr][6]);
                        acc[rr][7] = fmaf(xvv, wa1.w, acc[rr][7]);
                    }
                }
            }
        }
    }
    float* Bp = B + (size_t)(b*NACT+a)*8*4096;
    #pragma unroll
    for (int rr=0; rr<2; rr++) {
        int y = r0 + tl*2 + rr;
        #pragma unroll
        for (int n=0;n<8;n++)
            Bp[n*4096 + y*64 + col] = fmaxf(acc[rr][n] + b30[n], 0.f);
    }
}

// ---------------- K4a: fs2 partial over 128-L chunk; (n,c) per thread -------------
// x tile staged coalesced to LDS; B read from global (32 lanes share address =>
// hardware broadcast). One private dot + one atomicAdd per thread. 16.9 KB LDS.
__global__ __launch_bounds__(256) void k_fs2a(
        const float* __restrict__ x, const float* __restrict__ B,
        float* __restrict__ fs2g, Maps m) {
    int blk = blockIdx.x;   // b*30+a
    int rt = blockIdx.y;    // 0..31 -> L chunk [rt*128, rt*128+128)
    int a = blk % NACT, b = blk / NACT;
    int k = m.act_k[a];
    int spi = m.src_i[k], spj = m.src_j[k];
    int l0 = rt*128;

    __shared__ __align__(16) float xs[32*132];   // [c][132]; 33 f4 per channel

    int t = threadIdx.x;
    const float* xb = x + (size_t)b*32*HW*HW;
    #pragma unroll
    for (int q4 = 0; q4 < 4; q4++) {
        int idx = t + 256*q4;          // 0..1023
        int c = idx >> 5, lq = idx & 31;
        int l = l0 + lq*4;
        int y = l >> 6, xx = l & 63;
        float4 v = *(const float4*)(xb + (size_t)c*HW*HW + (size_t)(spi*64+y)*HW + spj*64 + xx);
        *(float4*)(xs + c*132 + lq*4) = v;
    }
    __syncthreads();

    int n = t >> 5, c = t & 31;
    const float4* Bg4 = (const float4*)(B + (size_t)(b*NACT+a)*8*4096 + (size_t)n*4096 + l0);
    const float4* xs4 = (const float4*)(xs + c*132);
    float facc = 0.f;
    #pragma unroll 8
    for (int q = 0; q < 32; q++) {
        float4 bv = Bg4[q];
        float4 xv = xs4[q];
        facc = fmaf(bv.x, xv.x, facc);
        facc = fmaf(bv.y, xv.y, facc);
        facc = fmaf(bv.z, xv.z, facc);
        facc = fmaf(bv.w, xv.w, facc);
    }
    atomicAdd(&fs2g[(size_t)(b*NACT+a)*256 + n*32 + c], facc);
}

// ---------------- K4b: fs2 -> fs3 -> fs5 -----------------------------------------
__global__ __launch_bounds__(256) void k_fs3(
        const float* __restrict__ fs2g,
        const float* __restrict__ w11, const float* __restrict__ b11,
        const float* __restrict__ w10, const float* __restrict__ b10,
        float* __restrict__ fs5, Maps m) {
    int blk = blockIdx.x;   // b*30+a
    int a = blk % NACT, b = blk / NACT;
    int k = m.act_k[a];
    __shared__ float fs2s[8*33], fs3s[8*33];
    int t = threadIdx.x;
    {
        int n = t >> 5, c = t & 31;
        fs2s[n*33+c] = fs2g[(size_t)(b*NACT+a)*256 + n*32 + c];
    }
    __syncthreads();
    {
        int o = t >> 5, c = t & 31;
        float v = b11[o];
        #pragma unroll
        for (int n=0;n<8;n++) v += w11[o*8+n]*fs2s[n*33+c];
        fs3s[o*33+c] = fmaxf(v, 0.f);
    }
    __syncthreads();
    {
        int cp = t >> 3, n = t & 7;
        float v = b10[cp];
        #pragma unroll
        for (int c=0;c<32;c++) v += w10[cp*32+c]*fs3s[n*33+c];
        fs5[((size_t)(b*64+k)*32 + cp)*8 + n] = fmaxf(v, 0.f);
    }
}

// ---------------- K5: fused fs6*g -> w31 -> BN -> relu -> +x -> out ---------------
// thread: r = t>>4 (row within 16-row tile), q = t&15 (4-px group); 32 o per thread
__global__ __launch_bounds__(256) void k_out(
        const float* __restrict__ x, const float* __restrict__ B,
        const float* __restrict__ fs5, const float* __restrict__ g,
        const float* __restrict__ w31, const float* __restrict__ b31,
        const float* __restrict__ gamma, const float* __restrict__ beta,
        const float* __restrict__ mean, const float* __restrict__ var,
        float* __restrict__ out, Maps m) {
    int blk = blockIdx.x;   // b*64 + ij
    int rt = blockIdx.y;    // 0..3
    int ij = blk & 63, b = blk >> 6;
    int i = ij >> 3, j = ij & 7;
    int K = (i+1)*(j+1) - 1;
    int aK = m.aidx[K];
    __shared__ float Ms[256];        // [o][n]
    __shared__ float ss2[32], sh2[32];
    int t = threadIdx.x;
    {
        int o = t >> 3, n = t & 7;
        const float* f5 = fs5 + (size_t)(b*64+K)*32*8;
        const float* gg = g + (size_t)(b*64+K)*32;
        float v = 0.f;
        #pragma unroll
        for (int c=0;c<32;c++) v += w31[o*32+c]*gg[c]*f5[c*8+n];
        Ms[o*8+n] = v;
    }
    if (t < 32) {
        float sc = rsqrtf(var[t] + 1e-5f) * gamma[t];
        ss2[t] = sc;
        sh2[t] = (b31[t] - mean[t])*sc + beta[t];   // fold conv bias + BN shift
    }
    __syncthreads();

    int r = t >> 4, q = t & 15;
    int y = rt*16 + r;
    int Y = i*64 + y;
    int X = j*64 + q*4;
    const float* Bp = B + (size_t)(b*NACT+aK)*8*4096 + y*64 + q*4;
    const float* xb = x + (size_t)b*32*HW*HW + (size_t)Y*HW + X;
    float* ob = out + (size_t)b*32*HW*HW + (size_t)Y*HW + X;

    float4 Bv[8];
    #pragma unroll
    for (int n=0;n<8;n++) Bv[n] = *(const float4*)(Bp + n*4096);

    #pragma unroll 4
    for (int o = 0; o < 32; o++) {
        float4 Ma = *(const float4*)(Ms + o*8);
        float4 Mb = *(const float4*)(Ms + o*8 + 4);
        float so = ss2[o], ho = sh2[o];
        float4 xv = *(const float4*)(xb + (size_t)o*HW*HW);
        float4 yv;
        yv.x = Bv[0].x*Ma.x + Bv[1].x*Ma.y + Bv[2].x*Ma.z + Bv[3].x*Ma.w
             + Bv[4].x*Mb.x + Bv[5].x*Mb.y + Bv[6].x*Mb.z + Bv[7].x*Mb.w;
        yv.y = Bv[0].y*Ma.x + Bv[1].y*Ma.y + Bv[2].y*Ma.z + Bv[3].y*Ma.w
             + Bv[4].y*Mb.x + Bv[5].y*Mb.y + Bv[6].y*Mb.z + Bv[7].y*Mb.w;
        yv.z = Bv[0].z*Ma.x + Bv[1].z*Ma.y + Bv[2].z*Ma.z + Bv[3].z*Ma.w
             + Bv[4].z*Mb.x + Bv[5].z*Mb.y + Bv[6].z*Mb.z + Bv[7].z*Mb.w;
        yv.w = Bv[0].w*Ma.x + Bv[1].w*Ma.y + Bv[2].w*Ma.z + Bv[3].w*Ma.w
             + Bv[4].w*Mb.x + Bv[5].w*Mb.y + Bv[6].w*Mb.z + Bv[7].w*Mb.w;
        float4 res;
        res.x = fmaxf(yv.x*so + ho, 0.f) + xv.x;
        res.y = fmaxf(yv.y*so + ho, 0.f) + xv.y;
        res.z = fmaxf(yv.z*so + ho, 0.f) + xv.z;
        res.w = fmaxf(yv.w*so + ho, 0.f) + xv.w;
        *(float4*)(ob + (size_t)o*HW*HW) = res;
    }
}

extern "C" void kernel_launch(void* const* d_in, const int* in_sizes, int n_in,
                              void* d_out, int out_size, void* d_ws, size_t ws_size,
                              hipStream_t stream) {
    const float* x    = (const float*)d_in[0];
    const float* w30  = (const float*)d_in[1];
    const float* b30  = (const float*)d_in[2];
    const float* w10  = (const float*)d_in[3];
    const float* b10  = (const float*)d_in[4];
    const float* w11  = (const float*)d_in[5];
    const float* b11  = (const float*)d_in[6];
    const float* w12a = (const float*)d_in[7];
    const float* b12a = (const float*)d_in[8];
    const float* w12b = (const float*)d_in[9];
    const float* b12b = (const float*)d_in[10];
    const float* w12c = (const float*)d_in[11];
    const float* b12c = (const float*)d_in[12];
    const float* w31  = (const float*)d_in[13];
    const float* b31  = (const float*)d_in[14];
    const float* gam  = (const float*)d_in[15];
    const float* bet  = (const float*)d_in[16];
    const float* mea  = (const float*)d_in[17];
    const float* var  = (const float*)d_in[18];
    float* out = (float*)d_out;

    float* ws   = (float*)d_ws;
    float* B    = ws;                       // 8*30*8*4096 = 7,864,320 floats
    float* fs5  = B + 7864320;              // 8*64*32*8   =   131,072
    float* fgw  = fs5 + 131072;             // 8*64*32     =    16,384
    float* g    = fgw + 16384;              // 8*64*32     =    16,384
    float* fs2g = g + 16384;                // 8*30*256    =    61,440

    static Maps m = make_maps();

    k_zero<<<dim3(240),     256, 0, stream>>>(fs2g, 61440);
    k_fg  <<<dim3(16384),   256, 0, stream>>>(x, fgw);
    k_g   <<<dim3(8),        64, 0, stream>>>(fgw, w12a, b12a, w12b, b12b, w12c, b12c, g);
    k_conv<<<dim3(240, 8),  256, 0, stream>>>(x, w30, b30, B, m);
    k_fs2a<<<dim3(240, 32), 256, 0, stream>>>(x, B, fs2g, m);
    k_fs3 <<<dim3(240),     256, 0, stream>>>(fs2g, w11, b11, w10, b10, fs5, m);
    k_out <<<dim3(512, 4),  256, 0, stream>>>(x, B, fs5, g, w31, b31, gam, bet, mea, var, out, m);
}